// Round 2
// baseline (8207.450 us; speedup 1.0000x reference)
//
#include <hip/hip_runtime.h>
#include <hip/hip_bf16.h>

// TemporalPropagator: complex Cayley (telescoping product: A skew-Hermitian,
// ||A|| ~ 0.64 so (I-A)^{-1}(I+A) = (I+A)^2 (I+A^2)(I+A^4)...(I+A^32),
// residual ||A||^64 ~ 4e-13), flux-tracker MLP (B=16), exponential-integrator
// coefficients, and three (4096x1024)x(1024x1024) complex GEMMs.
// ALL I/O IS FP32 (per reference dtypes); fp32 internal compute.

constexpr int Dn   = 1024;
constexpr int TBn  = 4096;
constexpr int Bn   = 16;
constexpr size_t DDsz = (size_t)Dn * Dn;        // 1,048,576
constexpr size_t TBD  = (size_t)TBn * Dn;       // 4,194,304
constexpr int OUT1 = 2 * TBn * Dn;              // offset of flux output in d_out

// ---------------- elementwise kernels ----------------

// A = 0.5*(raw_re - raw_re^T) + i*0.5*(raw_im + raw_im^T)
__global__ void build_A_k(const float* __restrict__ rre, const float* __restrict__ rim,
                          float* __restrict__ Are, float* __restrict__ Aim) {
  int idx = blockIdx.x * 256 + threadIdx.x;
  int i = idx >> 10, j = idx & 1023;
  Are[idx] = 0.5f * (rre[idx] - rre[j * Dn + i]);
  Aim[idx] = 0.5f * (rim[idx] + rim[j * Dn + i]);
}

// T0 = I + 2A + A^2   ( = (I+A)^2 )
__global__ void t0_k(const float* __restrict__ Are, const float* __restrict__ Aim,
                     const float* __restrict__ A2re, const float* __restrict__ A2im,
                     float* __restrict__ Tre, float* __restrict__ Tim) {
  int idx = blockIdx.x * 256 + threadIdx.x;
  int i = idx >> 10, j = idx & 1023;
  Tre[idx] = (i == j ? 1.f : 0.f) + 2.f * Are[idx] + A2re[idx];
  Tim[idx] = 2.f * Aim[idx] + A2im[idx];
}

// X = conj(U) * exp(sign*log_sigma)[col]
__global__ void scale_conj_k(const float* __restrict__ Ure, const float* __restrict__ Uim,
                             const float* __restrict__ ls, float sign,
                             float* __restrict__ Xre, float* __restrict__ Xim) {
  int idx = blockIdx.x * 256 + threadIdx.x;
  int j = idx & 1023;
  float sv = expf(sign * ls[j]);
  Xre[idx] =  Ure[idx] * sv;
  Xim[idx] = -Uim[idx] * sv;
}

// Wf = W1 * op_forcing[col] (complex); W1 <- W1 * op_decay[col] (in place)
__global__ void scale_cols_k(float* __restrict__ W1re, float* __restrict__ W1im,
                             const float* __restrict__ odr, const float* __restrict__ odi,
                             const float* __restrict__ ofr, const float* __restrict__ ofi,
                             float* __restrict__ Wfre, float* __restrict__ Wfim) {
  int idx = blockIdx.x * 256 + threadIdx.x;
  int j = idx & 1023;
  float wr = W1re[idx], wi = W1im[idx];
  float fr = ofr[j], fi = ofi[j], dr = odr[j], di = odi[j];
  Wfre[idx] = wr * fr - wi * fi;
  Wfim[idx] = wr * fi + wi * fr;
  W1re[idx] = wr * dr - wi * di;
  W1im[idx] = wr * di + wi * dr;
}

// exponential-integrator coefficients: op_decay = exp(Z), op_forcing = phi1(Z)*dt
__global__ void ops_k(const float* __restrict__ ld, const float* __restrict__ lf,
                      const float* __restrict__ lawre, const float* __restrict__ lawim,
                      const float* __restrict__ dtp,
                      float* __restrict__ odr, float* __restrict__ odi,
                      float* __restrict__ ofr, float* __restrict__ ofi) {
  int d = blockIdx.x * 256 + threadIdx.x;  // 1024 total
  float dt = dtp[0];                       // dt_eff = dt / DT_REF, DT_REF = 1
  float lre = -expf(ld[d]) + lawre[d];
  float lim = lf[d] + lawim[d];
  float Lre = -log1pf(expf(-lre));         // -softplus(-l_re)
  float zr = Lre * dt, zi = lim * dt;
  float er = expf(zr);
  float cz = cosf(zi), sz = sinf(zi);
  float Odr = er * cz, Odi = er * sz;      // exp(Z)
  float m2 = zr * zr + zi * zi;
  float p1r, p1i;
  if (sqrtf(m2) < 1e-4f) {                 // series 1 + Z/2 + Z^2/6
    p1r = 1.f + 0.5f * zr + (zr * zr - zi * zi) * (1.f / 6.f);
    p1i = 0.5f * zi + (2.f * zr * zi) * (1.f / 6.f);
  } else {                                 // (exp(Z)-1)/Z
    float nr = Odr - 1.f, ni = Odi;
    float inv = 1.f / m2;
    p1r = (nr * zr + ni * zi) * inv;
    p1i = (ni * zr - nr * zi) * inv;
  }
  odr[d] = Odr; odi[d] = Odi;
  ofr[d] = p1r * dt; ofi[d] = p1i * dt;    // phi1 * (dt_eff * DT_REF)
}

// x_mixed[b][o] = sum_c cat(xg_re,xg_im)[b][c] * mix_w[o][c] + mix_b[o]
__global__ void mix_k(const float* __restrict__ xgr, const float* __restrict__ xgi,
                      const float* __restrict__ W, const float* __restrict__ bias,
                      float* __restrict__ out) {
  int t = blockIdx.x * 256 + threadIdx.x;  // 16*2048
  int b = t >> 11, o = t & 2047;
  const float* wrow = W + (size_t)o * 2048;
  float acc = bias[o];
  for (int c = 0; c < Dn; c++) acc += xgr[b * Dn + c] * wrow[c];
  for (int c = 0; c < Dn; c++) acc += xgi[b * Dn + c] * wrow[Dn + c];
  out[t] = acc;
}

// flux_next = flux * (sigmoid(decay_re) + i decay_im) + (xr + i xi); writes output 1
__global__ void flux_k(const float* __restrict__ fre, const float* __restrict__ fim,
                       const float* __restrict__ dre, const float* __restrict__ dim_,
                       const float* __restrict__ xm,
                       float* __restrict__ fnre, float* __restrict__ fnim,
                       float* __restrict__ outf) {
  int t = blockIdx.x * 256 + threadIdx.x;  // B*D
  int b = t >> 10, d = t & 1023;
  float dr = 1.f / (1.f + expf(-dre[d]));
  float di = dim_[d];
  float fr = fre[t], fi = fim[t];
  float xr = xm[b * 2048 + d], xi = xm[b * 2048 + Dn + d];
  float nr = fr * dr - fi * di + xr;
  float ni = fr * di + fi * dr + xi;
  fnre[t] = nr; fnim[t] = ni;
  outf[OUT1 + t] = nr;
  outf[OUT1 + Bn * Dn + t] = ni;
}

// source = split( cat(fn_re,fn_im) @ proj_w^T + proj_b )
__global__ void proj_k(const float* __restrict__ fnre, const float* __restrict__ fnim,
                       const float* __restrict__ W, const float* __restrict__ bias,
                       float* __restrict__ sre, float* __restrict__ sim) {
  int t = blockIdx.x * 256 + threadIdx.x;  // 16*2048
  int b = t >> 11, o = t & 2047;
  const float* wrow = W + (size_t)o * 2048;
  float acc = bias[o];
  for (int c = 0; c < Dn; c++) acc += fnre[b * Dn + c] * wrow[c];
  for (int c = 0; c < Dn; c++) acc += fnim[b * Dn + c] * wrow[Dn + c];
  if (o < Dn) sre[b * Dn + o] = acc;
  else        sim[b * Dn + (o - Dn)] = acc;
}

// srcf = source * op_forcing (complex)
__global__ void srcf_k(const float* __restrict__ sre, const float* __restrict__ sim,
                       const float* __restrict__ ofr, const float* __restrict__ ofi,
                       float* __restrict__ tre, float* __restrict__ tim) {
  int t = blockIdx.x * 256 + threadIdx.x;  // B*D
  int d = t & 1023;
  float sr = sre[t], si = sim[t], fr = ofr[d], fi = ofi[d];
  tre[t] = sr * fr - si * fi;
  tim[t] = sr * fi + si * fr;
}

// ---------------- complex tiled GEMM ----------------
// C[M,N] = X[M,K] @ Y[K,N]  (NT: @ Y^T with Y[N,K])
//   + X (ADDX, square case: T + T@P) + C (BETA) + srcf bcast (SRC)
constexpr int BM = 64, BN = 64, BK = 16;

template <bool NT, bool ADDX, bool BETA, bool SRC>
__launch_bounds__(256)
__global__ void cgemm_k(const float* __restrict__ Xre, const float* __restrict__ Xim,
                        const float* __restrict__ Yre, const float* __restrict__ Yim,
                        float* __restrict__ Cre, float* __restrict__ Cim,
                        const float* __restrict__ Sre, const float* __restrict__ Sim,
                        int M, int K, int N) {
  __shared__ __align__(16) float Xs[2][BK][BM + 4];
  __shared__ __align__(16) float Ys[2][BK][BN + 4];
  const int tid = threadIdx.x;
  const int row0 = blockIdx.y * BM, col0 = blockIdx.x * BN;
  const int ty = tid >> 4, tx = tid & 15;
  float cr[4][4] = {}, ci[4][4] = {};

  for (int k0 = 0; k0 < K; k0 += BK) {
    {  // X tile (transposed into LDS): Xs[k][row]
      const int c = tid & 15;
      for (int rr = tid >> 4; rr < BM; rr += 16) {
        const int g = (row0 + rr) * K + k0 + c;
        Xs[0][c][rr] = Xre[g];
        Xs[1][c][rr] = Xim[g];
      }
    }
    if (NT) {  // Ys[k][j] = Y[col0+j][k0+k]
      const int c = tid & 15;
      for (int jj = tid >> 4; jj < BN; jj += 16) {
        const int g = (col0 + jj) * K + k0 + c;
        Ys[0][c][jj] = Yre[g];
        Ys[1][c][jj] = Yim[g];
      }
    } else {   // Ys[k][j] = Y[k0+k][col0+j]
      const int j = tid & 63;
      for (int c = tid >> 6; c < BK; c += 4) {
        const int g = (k0 + c) * N + col0 + j;
        Ys[0][c][j] = Yre[g];
        Ys[1][c][j] = Yim[g];
      }
    }
    __syncthreads();
    for (int k = 0; k < BK; k++) {
      float4 axr = *(const float4*)&Xs[0][k][ty * 4];
      float4 axi = *(const float4*)&Xs[1][k][ty * 4];
      float4 byr = *(const float4*)&Ys[0][k][tx * 4];
      float4 byi = *(const float4*)&Ys[1][k][tx * 4];
      float ar[4] = {axr.x, axr.y, axr.z, axr.w}, ai[4] = {axi.x, axi.y, axi.z, axi.w};
      float br[4] = {byr.x, byr.y, byr.z, byr.w}, bi4[4] = {byi.x, byi.y, byi.z, byi.w};
      for (int a = 0; a < 4; a++)
        for (int b = 0; b < 4; b++) {
          cr[a][b] += ar[a] * br[b] - ai[a] * bi4[b];
          ci[a][b] += ar[a] * bi4[b] + ai[a] * br[b];
        }
    }
    __syncthreads();
  }

  for (int a = 0; a < 4; a++) {
    const int gr = row0 + ty * 4 + a;
    for (int b = 0; b < 4; b++) {
      const int gc = col0 + tx * 4 + b;
      const int gi = gr * N + gc;
      float vr = cr[a][b], vi = ci[a][b];
      if constexpr (ADDX) { vr += Xre[gi]; vi += Xim[gi]; }  // M==K==N
      if constexpr (BETA) { vr += Cre[gi]; vi += Cim[gi]; }
      if constexpr (SRC)  { const int sb = gr >> 8; vr += Sre[sb * Dn + gc]; vi += Sim[sb * Dn + gc]; }
      Cre[gi] = vr; Cim[gi] = vi;
    }
  }
}

// ---------------- host-side helpers ----------------
static inline void cg_nn(const float* X, const float* Y, float* C, hipStream_t s) {
  cgemm_k<false, false, false, false><<<dim3(Dn / BN, Dn / BM), 256, 0, s>>>(
      X, X + DDsz, Y, Y + DDsz, C, C + DDsz, nullptr, nullptr, Dn, Dn, Dn);
}
static inline void cg_addx(const float* T, const float* P, float* C, hipStream_t s) {
  cgemm_k<false, true, false, false><<<dim3(Dn / BN, Dn / BM), 256, 0, s>>>(
      T, T + DDsz, P, P + DDsz, C, C + DDsz, nullptr, nullptr, Dn, Dn, Dn);
}
static inline void cg_nt(const float* X, const float* Y, float* C, hipStream_t s) {
  cgemm_k<true, false, false, false><<<dim3(Dn / BN, Dn / BM), 256, 0, s>>>(
      X, X + DDsz, Y, Y + DDsz, C, C + DDsz, nullptr, nullptr, Dn, Dn, Dn);
}

extern "C" void kernel_launch(void* const* d_in, const int* in_sizes, int n_in,
                              void* d_out, int out_size, void* d_ws, size_t ws_size,
                              hipStream_t stream) {
  (void)in_sizes; (void)n_in; (void)out_size; (void)ws_size;
  const float* h_re  = (const float*)d_in[0];
  const float* h_im  = (const float*)d_in[1];
  const float* x_re  = (const float*)d_in[2];
  const float* x_im  = (const float*)d_in[3];
  const float* xg_re = (const float*)d_in[4];
  const float* xg_im = (const float*)d_in[5];
  const float* fl_re = (const float*)d_in[6];
  const float* fl_im = (const float*)d_in[7];
  const float* dtp   = (const float*)d_in[8];
  const float* u_rre = (const float*)d_in[9];
  const float* u_rim = (const float*)d_in[10];
  const float* v_rre = (const float*)d_in[11];
  const float* v_rim = (const float*)d_in[12];
  const float* lsig  = (const float*)d_in[13];
  const float* dcre  = (const float*)d_in[14];
  const float* dcim  = (const float*)d_in[15];
  const float* mixw  = (const float*)d_in[16];
  const float* mixb  = (const float*)d_in[17];
  const float* projw = (const float*)d_in[18];
  const float* projb = (const float*)d_in[19];
  const float* ld_   = (const float*)d_in[20];
  const float* lf_   = (const float*)d_in[21];
  const float* lawre = (const float*)d_in[22];
  const float* lawim = (const float*)d_in[23];
  float* outf = (float*)d_out;

  float* w = (float*)d_ws;
  size_t off = 0;
  auto alloc = [&](size_t n) { float* p = w + off; off += n; return p; };
  float* f[7];
  for (int i = 0; i < 7; i++) f[i] = alloc(2 * DDsz);   // 7 complex DxD buffers
  float* ht   = alloc(2 * TBD);                          // h_next_tilde
  float* xm   = alloc((size_t)Bn * 2048);
  float* fnre = alloc((size_t)Bn * Dn);
  float* fnim = alloc((size_t)Bn * Dn);
  float* sre  = alloc((size_t)Bn * Dn);
  float* sim  = alloc((size_t)Bn * Dn);
  float* sfre = alloc((size_t)Bn * Dn);
  float* sfim = alloc((size_t)Bn * Dn);
  float* odr = alloc(Dn); float* odi = alloc(Dn);
  float* ofr = alloc(Dn); float* ofi = alloc(Dn);
  // total ~92.8 MB of ws

  // ---- Cayley: out = (I+A)^2 (I+A^2)(I+A^4)(I+A^8)(I+A^16)(I+A^32) ----
  auto cayley = [&](const float* rre, const float* rim, float* out) {
    float* A = f[0];
    build_A_k<<<4096, 256, 0, stream>>>(rre, rim, A, A + DDsz);
    cg_nn(A, A, f[1], stream);                                            // A2
    t0_k<<<4096, 256, 0, stream>>>(A, A + DDsz, f[1], f[1] + DDsz,
                                   f[3], f[3] + DDsz);                    // T0 = (I+A)^2
    cg_nn(f[1], f[1], f[2], stream);                                      // A4
    cg_addx(f[3], f[1], f[4], stream);                                    // T1 = T0(I+A2)
    cg_nn(f[2], f[2], f[1], stream);                                      // A8
    cg_addx(f[4], f[2], f[3], stream);                                    // T2 = T1(I+A4)
    cg_nn(f[1], f[1], f[2], stream);                                      // A16
    cg_addx(f[3], f[1], f[4], stream);                                    // T3 = T2(I+A8)
    cg_nn(f[2], f[2], f[1], stream);                                      // A32
    cg_addx(f[4], f[2], f[3], stream);                                    // T4 = T3(I+A16)
    cg_addx(f[3], f[1], out, stream);                                     // T5 = T4(I+A32)
  };
  cayley(u_rre, u_rim, f[5]);   // U
  cayley(v_rre, v_rim, f[6]);   // V

  // ---- small path: ops, flux tracker ----
  ops_k<<<4, 256, 0, stream>>>(ld_, lf_, lawre, lawim, dtp, odr, odi, ofr, ofi);
  mix_k<<<128, 256, 0, stream>>>(xg_re, xg_im, mixw, mixb, xm);
  flux_k<<<64, 256, 0, stream>>>(fl_re, fl_im, dcre, dcim, xm, fnre, fnim, outf);
  proj_k<<<128, 256, 0, stream>>>(fnre, fnim, projw, projb, sre, sim);
  srcf_k<<<64, 256, 0, stream>>>(sre, sim, ofr, ofi, sfre, sfim);

  // ---- W1 = M_inv^T = (conj(U) diag(s_inv)) @ V^T ; W2 = M^T = (conj(V) diag(s)) @ U^T ----
  scale_conj_k<<<4096, 256, 0, stream>>>(f[5], f[5] + DDsz, lsig, -1.f, f[0], f[0] + DDsz);
  cg_nt(f[0], f[6], f[1], stream);                                        // W1
  scale_cols_k<<<4096, 256, 0, stream>>>(f[1], f[1] + DDsz, odr, odi, ofr, ofi,
                                         f[2], f[2] + DDsz);              // f[1]=W1d, f[2]=W1f
  scale_conj_k<<<4096, 256, 0, stream>>>(f[6], f[6] + DDsz, lsig, +1.f, f[0], f[0] + DDsz);
  cg_nt(f[0], f[5], f[3], stream);                                        // W2

  // ---- big path ----
  // ht = h @ W1d
  cgemm_k<false, false, false, false><<<dim3(Dn / BN, TBn / BM), 256, 0, stream>>>(
      h_re, h_im, f[1], f[1] + DDsz, ht, ht + TBD, nullptr, nullptr, TBn, Dn, Dn);
  // ht += x @ W1f + srcf (broadcast per 256-row block)
  cgemm_k<false, false, true, true><<<dim3(Dn / BN, TBn / BM), 256, 0, stream>>>(
      x_re, x_im, f[2], f[2] + DDsz, ht, ht + TBD, sfre, sfim, TBn, Dn, Dn);
  // out = ht @ W2 -> fp32 split planes in d_out
  cgemm_k<false, false, false, false><<<dim3(Dn / BN, TBn / BM), 256, 0, stream>>>(
      ht, ht + TBD, f[3], f[3] + DDsz, outf, outf + TBD, nullptr, nullptr, TBn, Dn, Dn);
}

// Round 3
// 1090.616 us; speedup vs baseline: 7.5255x; 7.5255x over previous
//
#include <hip/hip_runtime.h>

// TemporalPropagator on MI355X — bf16-MFMA implementation.
// Cayley via telescoping product (A skew-Herm, ||A||~0.64):
//   (I-A)^-1 (I+A) = (I+A)^2 (I+A^2)(I+A^4)(I+A^8)(I+A^16)  [resid ~6e-7]
// All GEMMs on v_mfma_f32_16x16x32_bf16 with split-bf16 (hi/lo) operands:
//   chain: split x split (12 MFMA / complex MAC); big TB GEMMs: single x split (8).
// Structure tricks: Y-conjugation via register XOR of B-frags (YNEG template);
// U/V chains batched via gridDim.z=2; W1d/W1f + h/x fused into one K=2048 GEMM.

using s8v = __attribute__((ext_vector_type(8))) short;
using f4v = __attribute__((ext_vector_type(4))) float;

constexpr int Dn = 1024, TBn = 4096, Bn = 16;
constexpr size_t DD  = (size_t)Dn * Dn;
constexpr size_t TBD = (size_t)TBn * Dn;
constexpr int OUT1 = 2 * TBn * Dn;

#define MFMA(a, b, c) __builtin_amdgcn_mfma_f32_16x16x32_bf16(a, b, c, 0, 0, 0)

__device__ __forceinline__ short f2bf(float v) {
  unsigned u = __float_as_uint(v);
  return (short)((u + 0x7fffu + ((u >> 16) & 1u)) >> 16);
}
__device__ __forceinline__ float bf2f(short s) {
  return __uint_as_float(((unsigned)(unsigned short)s) << 16);
}
__device__ __forceinline__ void split2(float v, short& h, short& l) {
  h = f2bf(v); l = f2bf(v - bf2f(h));
}

// ---------------- elementwise: split-bf16 producers ----------------

// A = 0.5(G - G^T) + i*0.5(H + H^T), split planes (rh, rl, ih, il)
__global__ void build_A4_k(const float* __restrict__ rre, const float* __restrict__ rim,
                           short* __restrict__ o0, short* __restrict__ o1,
                           short* __restrict__ o2, short* __restrict__ o3) {
  int idx = blockIdx.x * 256 + threadIdx.x;
  int i = idx >> 10, j = idx & 1023;
  float ar = 0.5f * (rre[idx] - rre[j * Dn + i]);
  float ai = 0.5f * (rim[idx] + rim[j * Dn + i]);
  short h, l;
  split2(ar, h, l); o0[idx] = h; o1[idx] = l;
  split2(ai, h, l); o2[idx] = h; o3[idx] = l;
}

// T0 = I + 2A + A2
__global__ void t04_k(const short* __restrict__ a0, const short* __restrict__ a1,
                      const short* __restrict__ a2, const short* __restrict__ a3,
                      const short* __restrict__ p0, const short* __restrict__ p1,
                      const short* __restrict__ p2, const short* __restrict__ p3,
                      short* __restrict__ o0, short* __restrict__ o1,
                      short* __restrict__ o2, short* __restrict__ o3) {
  int idx = blockIdx.x * 256 + threadIdx.x;
  int i = idx >> 10, j = idx & 1023;
  float vr = (i == j ? 1.f : 0.f) + 2.f * (bf2f(a0[idx]) + bf2f(a1[idx]))
           + bf2f(p0[idx]) + bf2f(p1[idx]);
  float vi = 2.f * (bf2f(a2[idx]) + bf2f(a3[idx])) + bf2f(p2[idx]) + bf2f(p3[idx]);
  short h, l;
  split2(vr, h, l); o0[idx] = h; o1[idx] = l;
  split2(vi, h, l); o2[idx] = h; o3[idx] = l;
}

// X' = U * exp(sgn*log_sigma)[col]  (real column scale)
__global__ void colscale_k(const short* __restrict__ u0, const short* __restrict__ u1,
                           const short* __restrict__ u2, const short* __restrict__ u3,
                           const float* __restrict__ ls, float sgn,
                           short* __restrict__ o0, short* __restrict__ o1,
                           short* __restrict__ o2, short* __restrict__ o3) {
  int idx = blockIdx.x * 256 + threadIdx.x;
  int j = idx & 1023;
  float sv = expf(sgn * ls[j]);
  float vr = (bf2f(u0[idx]) + bf2f(u1[idx])) * sv;
  float vi = (bf2f(u2[idx]) + bf2f(u3[idx])) * sv;
  short h, l;
  split2(vr, h, l); o0[idx] = h; o1[idx] = l;
  split2(vi, h, l); o2[idx] = h; o3[idx] = l;
}

// W1buf[n][k]      = Minv[n][k] * op_decay[n]   (complex)
// W1buf[n][1024+k] = Minv[n][k] * op_forcing[n]
__global__ void w1build_k(const short* __restrict__ m0, const short* __restrict__ m1,
                          const short* __restrict__ m2, const short* __restrict__ m3,
                          const float* __restrict__ odr, const float* __restrict__ odi,
                          const float* __restrict__ ofr, const float* __restrict__ ofi,
                          short* __restrict__ w0, short* __restrict__ w1,
                          short* __restrict__ w2, short* __restrict__ w3) {
  int idx = blockIdx.x * 256 + threadIdx.x;
  int n = idx >> 10, k = idx & 1023;
  float vr = bf2f(m0[idx]) + bf2f(m1[idx]);
  float vi = bf2f(m2[idx]) + bf2f(m3[idx]);
  size_t d0 = (size_t)n * 2048 + k, d1 = d0 + 1024;
  short h, l;
  float dr = odr[n], di = odi[n], fr = ofr[n], fi = ofi[n];
  split2(vr * dr - vi * di, h, l); w0[d0] = h; w1[d0] = l;
  split2(vr * di + vi * dr, h, l); w2[d0] = h; w3[d0] = l;
  split2(vr * fr - vi * fi, h, l); w0[d1] = h; w1[d1] = l;
  split2(vr * fi + vi * fr, h, l); w2[d1] = h; w3[d1] = l;
}

// fp32 -> single-bf16 planes (re, im)
__global__ void conv2_k(const float* __restrict__ re, const float* __restrict__ im,
                        short* __restrict__ orh, short* __restrict__ oih) {
  int idx = blockIdx.x * 256 + threadIdx.x;
  orh[idx] = f2bf(re[idx]);
  oih[idx] = f2bf(im[idx]);
}

// ---------------- fp32 small path ----------------

__global__ void ops_k(const float* __restrict__ ld, const float* __restrict__ lf,
                      const float* __restrict__ lawre, const float* __restrict__ lawim,
                      const float* __restrict__ dtp,
                      float* __restrict__ odr, float* __restrict__ odi,
                      float* __restrict__ ofr, float* __restrict__ ofi) {
  int d = blockIdx.x * 256 + threadIdx.x;
  float dt = dtp[0];
  float lre = -expf(ld[d]) + lawre[d];
  float lim = lf[d] + lawim[d];
  float Lre = -log1pf(expf(-lre));
  float zr = Lre * dt, zi = lim * dt;
  float er = expf(zr);
  float Odr = er * cosf(zi), Odi = er * sinf(zi);
  float m2 = zr * zr + zi * zi;
  float p1r, p1i;
  if (sqrtf(m2) < 1e-4f) {
    p1r = 1.f + 0.5f * zr + (zr * zr - zi * zi) * (1.f / 6.f);
    p1i = 0.5f * zi + (2.f * zr * zi) * (1.f / 6.f);
  } else {
    float nr = Odr - 1.f, ni = Odi, inv = 1.f / m2;
    p1r = (nr * zr + ni * zi) * inv;
    p1i = (ni * zr - nr * zi) * inv;
  }
  odr[d] = Odr; odi[d] = Odi;
  ofr[d] = p1r * dt; ofi[d] = p1i * dt;
}

// wave-per-output MLP: out[b][o] = cat(in0,in1)[b] . W[o] + bias[o]
template <bool SPLIT>
__global__ void mlpw_k(const float* __restrict__ in0, const float* __restrict__ in1,
                       const float* __restrict__ W, const float* __restrict__ bias,
                       float* __restrict__ out0, float* __restrict__ out1) {
  int wid = blockIdx.x * 4 + (threadIdx.x >> 6);
  int lane = threadIdx.x & 63;
  int b = wid >> 11, o = wid & 2047;
  const float* w0 = W + (size_t)o * 2048;
  float acc = 0.f;
  for (int c = lane; c < Dn; c += 64)
    acc += in0[b * Dn + c] * w0[c] + in1[b * Dn + c] * w0[Dn + c];
  for (int s = 32; s; s >>= 1) acc += __shfl_xor(acc, s);
  if (lane == 0) {
    acc += bias[o];
    if (SPLIT) {
      if (o < Dn) out0[b * Dn + o] = acc;
      else        out1[b * Dn + (o - Dn)] = acc;
    } else out0[b * 2048 + o] = acc;
  }
}

__global__ void flux_k(const float* __restrict__ fre, const float* __restrict__ fim,
                       const float* __restrict__ dre, const float* __restrict__ dim_,
                       const float* __restrict__ xm,
                       float* __restrict__ fnre, float* __restrict__ fnim,
                       float* __restrict__ outf) {
  int t = blockIdx.x * 256 + threadIdx.x;
  int b = t >> 10, d = t & 1023;
  float dr = 1.f / (1.f + expf(-dre[d]));
  float di = dim_[d];
  float fr = fre[t], fi = fim[t];
  float xr = xm[b * 2048 + d], xi = xm[b * 2048 + Dn + d];
  float nr = fr * dr - fi * di + xr;
  float ni = fr * di + fi * dr + xi;
  fnre[t] = nr; fnim[t] = ni;
  outf[OUT1 + t] = nr;
  outf[OUT1 + Bn * Dn + t] = ni;
}

__global__ void srcf_k(const float* __restrict__ sre, const float* __restrict__ sim,
                       const float* __restrict__ ofr, const float* __restrict__ ofi,
                       float* __restrict__ tre, float* __restrict__ tim) {
  int t = blockIdx.x * 256 + threadIdx.x;
  int d = t & 1023;
  float sr = sre[t], si = sim[t], fr = ofr[d], fi = ofi[d];
  tre[t] = sr * fr - si * fi;
  tim[t] = sr * fi + si * fr;
}

// ---------------- MFMA complex GEMM ----------------
// C[M][N] = sum_k X[m][k] * Y[k][n]; Y read from SY stored [N][K] (SY = Y^T).
// X planes: (rh, rl, ih, il) split (XS=0) or (rh, ih) single (XS=1).
// YNEG: 0 none, 1 negate im of Y-frags (conj), 2 negate re (-conj; skew-Herm A).
// OUT: 0 split4 planes, 1 single2 planes, 2 fp32 re/im.
struct MGP {
  const short* X[2][4];
  const short* X2p[2][4];   // second X set (k >= Kx) when X2
  const short* Y[2][4];
  short* O[2][4];
  float* OF[2][2];
  const float* S[2][2];
  int M, K, N, Kx;
};

template <int MI, int NI, int XS, int X2, int ADDX, int SRC, int OUT, int YNEG>
__launch_bounds__(256, (MI == 2 ? 3 : 2))
__global__ void mgemm_k(MGP g) {
  constexpr int BM = MI * 32, BN = NI * 32;
  constexpr int NPX = XS ? 2 : 4;
  __shared__ __align__(16) short As[NPX][BM * 32];
  __shared__ __align__(16) short Bs[4][BN * 32];
  const int tid = threadIdx.x;
  const int lane = tid & 63, wave = tid >> 6;
  const int wm = wave >> 1, wn = wave & 1;
  const int bz = blockIdx.z;
  const int row0 = blockIdx.y * BM, col0 = blockIdx.x * BN;
  const int fl = lane & 15, fq = lane >> 4;
  const int K = g.K, N = g.N, Kx = g.Kx;
  const int srow = lane >> 2;
  const int schunk = (lane & 3) * 8;

  s8v sgn;
  #pragma unroll
  for (int i = 0; i < 8; i++) sgn[i] = (short)0x8000;

  f4v aR[MI][NI], aI[MI][NI];
  #pragma unroll
  for (int m = 0; m < MI; m++)
    #pragma unroll
    for (int n = 0; n < NI; n++)
      #pragma unroll
      for (int r = 0; r < 4; r++) { aR[m][n][r] = 0.f; aI[m][n][r] = 0.f; }

  for (int k0 = 0; k0 < K; k0 += 32) {
    // ---- stage X planes (global -> LDS, 16B per lane, wave-uniform LDS base) ----
    const short* const* xset = g.X[bz];
    int kk = k0;
    if (X2) { if (k0 >= Kx) { xset = g.X2p[bz]; kk = k0 - Kx; } }
    #pragma unroll
    for (int p = 0; p < NPX; p++)
      #pragma unroll
      for (int u = 0; u < BM / 64; u++) {
        int r = wave * (BM / 4) + u * 16 + srow;
        const short* gp = xset[p] + (size_t)(row0 + r) * Kx + kk + schunk;
        short* lp = &As[p][(wave * (BM / 4) + u * 16) * 32];
        __builtin_amdgcn_global_load_lds((const __attribute__((address_space(1))) void*)gp,
                                         (__attribute__((address_space(3))) void*)lp, 16, 0, 0);
      }
    // ---- stage Y planes ----
    #pragma unroll
    for (int p = 0; p < 4; p++)
      #pragma unroll
      for (int u = 0; u < BN / 64; u++) {
        int r = wave * (BN / 4) + u * 16 + srow;
        const short* gp = g.Y[bz][p] + (size_t)(col0 + r) * K + k0 + schunk;
        short* lp = &Bs[p][(wave * (BN / 4) + u * 16) * 32];
        __builtin_amdgcn_global_load_lds((const __attribute__((address_space(1))) void*)gp,
                                         (__attribute__((address_space(3))) void*)lp, 16, 0, 0);
      }
    __syncthreads();

    // ---- B fragments (B[k][n]: n = lane&15, k = (lane>>4)*8 + j) ----
    s8v bf[NI][4];
    #pragma unroll
    for (int n = 0; n < NI; n++)
      #pragma unroll
      for (int p = 0; p < 4; p++)
        bf[n][p] = *(const s8v*)&Bs[p][(wn * NI * 16 + n * 16 + fl) * 32 + fq * 8];
    if constexpr (YNEG == 1) {
      #pragma unroll
      for (int n = 0; n < NI; n++) { bf[n][2] ^= sgn; bf[n][3] ^= sgn; }
    } else if constexpr (YNEG == 2) {
      #pragma unroll
      for (int n = 0; n < NI; n++) { bf[n][0] ^= sgn; bf[n][1] ^= sgn; }
    }

    // ---- compute ----
    #pragma unroll
    for (int m = 0; m < MI; m++) {
      int arow = (wm * MI * 16 + m * 16 + fl) * 32 + fq * 8;
      if constexpr (XS) {
        s8v arh = *(const s8v*)&As[0][arow];
        s8v aih = *(const s8v*)&As[1][arow];
        s8v nih = aih ^ sgn;
        #pragma unroll
        for (int n = 0; n < NI; n++) {
          f4v cr = aR[m][n], ci = aI[m][n];
          cr = MFMA(arh, bf[n][0], cr); cr = MFMA(arh, bf[n][1], cr);
          cr = MFMA(nih, bf[n][2], cr); cr = MFMA(nih, bf[n][3], cr);
          ci = MFMA(arh, bf[n][2], ci); ci = MFMA(arh, bf[n][3], ci);
          ci = MFMA(aih, bf[n][0], ci); ci = MFMA(aih, bf[n][1], ci);
          aR[m][n] = cr; aI[m][n] = ci;
        }
      } else {
        s8v arh = *(const s8v*)&As[0][arow];
        s8v arl = *(const s8v*)&As[1][arow];
        s8v aih = *(const s8v*)&As[2][arow];
        s8v ail = *(const s8v*)&As[3][arow];
        s8v nih = aih ^ sgn;
        s8v nil = ail ^ sgn;
        #pragma unroll
        for (int n = 0; n < NI; n++) {
          f4v cr = aR[m][n], ci = aI[m][n];
          cr = MFMA(arh, bf[n][0], cr); cr = MFMA(arh, bf[n][1], cr);
          cr = MFMA(arl, bf[n][0], cr);
          cr = MFMA(nih, bf[n][2], cr); cr = MFMA(nih, bf[n][3], cr);
          cr = MFMA(nil, bf[n][2], cr);
          ci = MFMA(arh, bf[n][2], ci); ci = MFMA(arh, bf[n][3], ci);
          ci = MFMA(arl, bf[n][2], ci);
          ci = MFMA(aih, bf[n][0], ci); ci = MFMA(aih, bf[n][1], ci);
          ci = MFMA(ail, bf[n][0], ci);
          aR[m][n] = cr; aI[m][n] = ci;
        }
      }
    }
    __syncthreads();
  }

  // ---- epilogue: C/D layout col = lane&15, row = (lane>>4)*4 + reg ----
  #pragma unroll
  for (int m = 0; m < MI; m++) {
    #pragma unroll
    for (int n = 0; n < NI; n++) {
      int grb = row0 + wm * MI * 16 + m * 16 + fq * 4;
      int gc  = col0 + wn * NI * 16 + n * 16 + fl;
      #pragma unroll
      for (int r = 0; r < 4; r++) {
        int gr = grb + r;
        size_t gi = (size_t)gr * N + gc;
        float vr = aR[m][n][r], vi = aI[m][n][r];
        if constexpr (ADDX) {
          vr += bf2f(g.X[bz][0][gi]) + bf2f(g.X[bz][1][gi]);
          vi += bf2f(g.X[bz][2][gi]) + bf2f(g.X[bz][3][gi]);
        }
        if constexpr (SRC) {
          int sb = gr >> 8;
          vr += g.S[bz][0][sb * Dn + gc];
          vi += g.S[bz][1][sb * Dn + gc];
        }
        if constexpr (OUT == 0) {
          short h, l;
          split2(vr, h, l); g.O[bz][0][gi] = h; g.O[bz][1][gi] = l;
          split2(vi, h, l); g.O[bz][2][gi] = h; g.O[bz][3][gi] = l;
        } else if constexpr (OUT == 1) {
          g.O[bz][0][gi] = f2bf(vr);
          g.O[bz][1][gi] = f2bf(vi);
        } else {
          g.OF[bz][0][gi] = vr;
          g.OF[bz][1][gi] = vi;
        }
      }
    }
  }
}

// ---------------- host ----------------

extern "C" void kernel_launch(void* const* d_in, const int* in_sizes, int n_in,
                              void* d_out, int out_size, void* d_ws, size_t ws_size,
                              hipStream_t stream) {
  (void)in_sizes; (void)n_in; (void)out_size; (void)ws_size;
  const float* h_re  = (const float*)d_in[0];
  const float* h_im  = (const float*)d_in[1];
  const float* x_re  = (const float*)d_in[2];
  const float* x_im  = (const float*)d_in[3];
  const float* xg_re = (const float*)d_in[4];
  const float* xg_im = (const float*)d_in[5];
  const float* fl_re = (const float*)d_in[6];
  const float* fl_im = (const float*)d_in[7];
  const float* dtp   = (const float*)d_in[8];
  const float* u_rre = (const float*)d_in[9];
  const float* u_rim = (const float*)d_in[10];
  const float* v_rre = (const float*)d_in[11];
  const float* v_rim = (const float*)d_in[12];
  const float* lsig  = (const float*)d_in[13];
  const float* dcre  = (const float*)d_in[14];
  const float* dcim  = (const float*)d_in[15];
  const float* mixw  = (const float*)d_in[16];
  const float* mixb  = (const float*)d_in[17];
  const float* projw = (const float*)d_in[18];
  const float* projb = (const float*)d_in[19];
  const float* ld_   = (const float*)d_in[20];
  const float* lf_   = (const float*)d_in[21];
  const float* lawre = (const float*)d_in[22];
  const float* lawim = (const float*)d_in[23];
  float* outf = (float*)d_out;

  short* wsS = (short*)d_ws;
  auto pl = [&](int i) { return wsS + (size_t)i * DD; };
  // plane map (1 unit = 1024x1024 bf16 = 2MB):
  //  0-3  A_u          (later XscV)       4-7  A_v          (later XscU)
  //  8-11 P0_u         (later Minv)      12-15 P0_v         (later M)
  // 16-19 P1_u  \__ later W1 [1024][2048] (units 16-23)
  // 20-23 P1_v  /
  // 24-27 Tb0_u, 28-31 Tb0_v  (later hp: rh 24-27, ih 28-31)
  // 32-35 Tb1_u, 36-39 Tb1_v  (later xp: rh 32-35, ih 36-39)
  // 40-43 U, 44-47 V           (later ht: rh 40-43, ih 44-47)
  float* fbase = (float*)(wsS + (size_t)48 * DD);
  float* xm   = fbase;
  float* fnre = xm + 32768;
  float* fnim = fnre + 16384;
  float* sre  = fnim + 16384;
  float* sim  = sre + 16384;
  float* sfre = sim + 16384;
  float* sfim = sfre + 16384;
  float* odr  = sfim + 16384;
  float* odi  = odr + Dn;
  float* ofr  = odi + Dn;
  float* ofi  = ofr + Dn;

  const dim3 blk(256);
  const dim3 gDD(16, 16, 2);

  // ---- build A (split planes) ----
  build_A4_k<<<4096, blk, 0, stream>>>(u_rre, u_rim, pl(0), pl(1), pl(2), pl(3));
  build_A4_k<<<4096, blk, 0, stream>>>(v_rre, v_rim, pl(4), pl(5), pl(6), pl(7));

  auto set4 = [&](const short** f, int base) { for (int i = 0; i < 4; i++) f[i] = pl(base + i); };
  auto set4o = [&](short** f, int base) { for (int i = 0; i < 4; i++) f[i] = pl(base + i); };

  // A2 = A @ A  (Y = A, SY = -conj(A) -> YNEG=2)  -> P0
  {
    MGP G{};
    set4(G.X[0], 0); set4(G.X[1], 4);
    set4(G.Y[0], 0); set4(G.Y[1], 4);
    set4o(G.O[0], 8); set4o(G.O[1], 12);
    G.M = G.K = G.N = G.Kx = 1024;
    mgemm_k<2,2,0,0,0,0,0,2><<<gDD, blk, 0, stream>>>(G);
  }
  // T0 = I + 2A + A2
  t04_k<<<4096, blk, 0, stream>>>(pl(0), pl(1), pl(2), pl(3), pl(8), pl(9), pl(10), pl(11),
                                  pl(24), pl(25), pl(26), pl(27));
  t04_k<<<4096, blk, 0, stream>>>(pl(4), pl(5), pl(6), pl(7), pl(12), pl(13), pl(14), pl(15),
                                  pl(28), pl(29), pl(30), pl(31));
  // helper for the chain GEMMs
  auto chain_pow = [&](int x0, int x1, int o0, int o1) {  // X=Y=P(x), Herm conj -> O
    MGP G{};
    set4(G.X[0], x0); set4(G.X[1], x1);
    set4(G.Y[0], x0); set4(G.Y[1], x1);
    set4o(G.O[0], o0); set4o(G.O[1], o1);
    G.M = G.K = G.N = G.Kx = 1024;
    mgemm_k<2,2,0,0,0,0,0,1><<<gDD, blk, 0, stream>>>(G);
  };
  auto chain_t = [&](int x0, int x1, int y0, int y1, int o0, int o1) {  // T' = T + T@P
    MGP G{};
    set4(G.X[0], x0); set4(G.X[1], x1);
    set4(G.Y[0], y0); set4(G.Y[1], y1);
    set4o(G.O[0], o0); set4o(G.O[1], o1);
    G.M = G.K = G.N = G.Kx = 1024;
    mgemm_k<2,2,0,0,1,0,0,1><<<gDD, blk, 0, stream>>>(G);
  };
  chain_pow(8, 12, 16, 20);           // A4  = A2*A2  -> P1
  chain_t(24, 28, 8, 12, 32, 36);     // T1  = T0(I+A2) -> Tb1
  chain_pow(16, 20, 8, 12);           // A8  = A4*A4  -> P0
  chain_t(32, 36, 16, 20, 24, 28);    // T2  = T1(I+A4) -> Tb0
  chain_pow(8, 12, 16, 20);           // A16 = A8*A8  -> P1
  chain_t(24, 28, 8, 12, 32, 36);     // T3  = T2(I+A8) -> Tb1
  chain_t(32, 36, 16, 20, 40, 44);    // T4  = T3(I+A16) -> U / V

  // ---- fp32 small path ----
  ops_k<<<4, blk, 0, stream>>>(ld_, lf_, lawre, lawim, dtp, odr, odi, ofr, ofi);
  mlpw_k<false><<<8192, blk, 0, stream>>>(xg_re, xg_im, mixw, mixb, xm, nullptr);
  flux_k<<<64, blk, 0, stream>>>(fl_re, fl_im, dcre, dcim, xm, fnre, fnim, outf);
  mlpw_k<true><<<8192, blk, 0, stream>>>(fnre, fnim, projw, projb, sre, sim);
  srcf_k<<<64, blk, 0, stream>>>(sre, sim, ofr, ofi, sfre, sfim);

  // ---- Minv = (V s^-1) conj(U)^T ; M = (U s) conj(V)^T  (batched) ----
  colscale_k<<<4096, blk, 0, stream>>>(pl(44), pl(45), pl(46), pl(47), lsig, -1.f,
                                       pl(0), pl(1), pl(2), pl(3));   // XscV
  colscale_k<<<4096, blk, 0, stream>>>(pl(40), pl(41), pl(42), pl(43), lsig, +1.f,
                                       pl(4), pl(5), pl(6), pl(7));   // XscU
  {
    MGP G{};
    set4(G.X[0], 0); set4(G.X[1], 4);
    set4(G.Y[0], 40); set4(G.Y[1], 44);   // conj via YNEG=1
    set4o(G.O[0], 8); set4o(G.O[1], 12);  // Minv -> 8-11, M -> 12-15
    G.M = G.K = G.N = G.Kx = 1024;
    mgemm_k<2,2,0,0,0,0,0,1><<<gDD, blk, 0, stream>>>(G);
  }
  // W1buf [1024][2048] = [Minv*od | Minv*of]
  w1build_k<<<4096, blk, 0, stream>>>(pl(8), pl(9), pl(10), pl(11), odr, odi, ofr, ofi,
                                      pl(16), pl(18), pl(20), pl(22));
  // h, x -> single-bf16 planes
  conv2_k<<<16384, blk, 0, stream>>>(h_re, h_im, pl(24), pl(28));
  conv2_k<<<16384, blk, 0, stream>>>(x_re, x_im, pl(32), pl(36));

  // ---- big GEMM 1: ht = [h|x] @ [W1d;W1f] + srcf  -> single-bf16 planes ----
  {
    MGP G{};
    G.X[0][0] = pl(24); G.X[0][1] = pl(28);
    G.X2p[0][0] = pl(32); G.X2p[0][1] = pl(36);
    G.Y[0][0] = pl(16); G.Y[0][1] = pl(18); G.Y[0][2] = pl(20); G.Y[0][3] = pl(22);
    G.O[0][0] = pl(40); G.O[0][1] = pl(44);
    G.S[0][0] = sfre; G.S[0][1] = sfim;
    G.M = 4096; G.K = 2048; G.N = 1024; G.Kx = 1024;
    mgemm_k<4,4,1,1,0,1,1,0><<<dim3(8, 32, 1), blk, 0, stream>>>(G);
  }
  // ---- big GEMM 2: out = ht @ M^T -> fp32 d_out ----
  {
    MGP G{};
    G.X[0][0] = pl(40); G.X[0][1] = pl(44);
    G.Y[0][0] = pl(12); G.Y[0][1] = pl(13); G.Y[0][2] = pl(14); G.Y[0][3] = pl(15);
    G.OF[0][0] = outf; G.OF[0][1] = outf + TBD;
    G.M = 4096; G.K = 1024; G.N = 1024; G.Kx = 1024;
    mgemm_k<4,4,1,0,0,0,2,0><<<dim3(8, 32, 1), blk, 0, stream>>>(G);
  }
}

// Round 4
// 757.284 us; speedup vs baseline: 10.8380x; 1.4402x over previous
//
#include <hip/hip_runtime.h>

// TemporalPropagator on MI355X — bf16-MFMA implementation, round 4.
// Cayley via telescoping product (A skew-Herm, ||A||~0.64):
//   (I-A)^-1 (I+A) = (I+A)^2 (I+A^2)(I+A^4)(I+A^8)(I+A^16)  [resid ~6e-7]
// Chain GEMMs: single-bf16 x single-bf16 (4 MFMA / complex MAC).
// Big TB GEMMs: single-bf16 X x split-bf16 Y (8 MFMA / MAC); W1, M kept split.
// Y-conjugation via register XOR of B-frags (YNEG); U/V chains batched via
// gridDim.z=2; W1d/W1f + h/x fused into one K=2048 GEMM; big tiles 128x64
// (512 blocks = 2/CU for barrier-drain overlap).

using s8v = __attribute__((ext_vector_type(8))) short;
using f4v = __attribute__((ext_vector_type(4))) float;

constexpr int Dn = 1024, TBn = 4096, Bn = 16;
constexpr size_t DD  = (size_t)Dn * Dn;
constexpr size_t TBD = (size_t)TBn * Dn;
constexpr int OUT1 = 2 * TBn * Dn;

#define MFMA(a, b, c) __builtin_amdgcn_mfma_f32_16x16x32_bf16(a, b, c, 0, 0, 0)

__device__ __forceinline__ short f2bf(float v) {
  unsigned u = __float_as_uint(v);
  return (short)((u + 0x7fffu + ((u >> 16) & 1u)) >> 16);
}
__device__ __forceinline__ float bf2f(short s) {
  return __uint_as_float(((unsigned)(unsigned short)s) << 16);
}
__device__ __forceinline__ void split2(float v, short& h, short& l) {
  h = f2bf(v); l = f2bf(v - bf2f(h));
}

// ---------------- elementwise producers ----------------

// A = 0.5(G - G^T) + i*0.5(H + H^T), single planes (re, im)
__global__ void build_A2_k(const float* __restrict__ rre, const float* __restrict__ rim,
                           short* __restrict__ o0, short* __restrict__ o1) {
  int idx = blockIdx.x * 256 + threadIdx.x;
  int i = idx >> 10, j = idx & 1023;
  o0[idx] = f2bf(0.5f * (rre[idx] - rre[j * Dn + i]));
  o1[idx] = f2bf(0.5f * (rim[idx] + rim[j * Dn + i]));
}

// T0 = I + 2A + A2 (single planes)
__global__ void t02_k(const short* __restrict__ a0, const short* __restrict__ a1,
                      const short* __restrict__ p0, const short* __restrict__ p1,
                      short* __restrict__ o0, short* __restrict__ o1) {
  int idx = blockIdx.x * 256 + threadIdx.x;
  int i = idx >> 10, j = idx & 1023;
  o0[idx] = f2bf((i == j ? 1.f : 0.f) + 2.f * bf2f(a0[idx]) + bf2f(p0[idx]));
  o1[idx] = f2bf(2.f * bf2f(a1[idx]) + bf2f(p1[idx]));
}

// X' = U * exp(sgn*log_sigma)[col]  (real column scale, single planes)
__global__ void colscale2_k(const short* __restrict__ u0, const short* __restrict__ u1,
                            const float* __restrict__ ls, float sgn,
                            short* __restrict__ o0, short* __restrict__ o1) {
  int idx = blockIdx.x * 256 + threadIdx.x;
  int j = idx & 1023;
  float sv = expf(sgn * ls[j]);
  o0[idx] = f2bf(bf2f(u0[idx]) * sv);
  o1[idx] = f2bf(bf2f(u1[idx]) * sv);
}

// W1buf[n][k] = Minv[n][k]*op_decay[n]; W1buf[n][1024+k] = Minv[n][k]*op_forcing[n]
// input Minv split (4 planes), output W1 split (4 planes, [1024][2048])
__global__ void w1build_k(const short* __restrict__ m0, const short* __restrict__ m1,
                          const short* __restrict__ m2, const short* __restrict__ m3,
                          const float* __restrict__ odr, const float* __restrict__ odi,
                          const float* __restrict__ ofr, const float* __restrict__ ofi,
                          short* __restrict__ w0, short* __restrict__ w1,
                          short* __restrict__ w2, short* __restrict__ w3) {
  int idx = blockIdx.x * 256 + threadIdx.x;
  int n = idx >> 10, k = idx & 1023;
  float vr = bf2f(m0[idx]) + bf2f(m1[idx]);
  float vi = bf2f(m2[idx]) + bf2f(m3[idx]);
  size_t d0 = (size_t)n * 2048 + k, d1 = d0 + 1024;
  short h, l;
  float dr = odr[n], di = odi[n], fr = ofr[n], fi = ofi[n];
  split2(vr * dr - vi * di, h, l); w0[d0] = h; w1[d0] = l;
  split2(vr * di + vi * dr, h, l); w2[d0] = h; w3[d0] = l;
  split2(vr * fr - vi * fi, h, l); w0[d1] = h; w1[d1] = l;
  split2(vr * fi + vi * fr, h, l); w2[d1] = h; w3[d1] = l;
}

// fp32 -> single-bf16 planes (re, im)
__global__ void conv2_k(const float* __restrict__ re, const float* __restrict__ im,
                        short* __restrict__ orh, short* __restrict__ oih) {
  int idx = blockIdx.x * 256 + threadIdx.x;
  orh[idx] = f2bf(re[idx]);
  oih[idx] = f2bf(im[idx]);
}

// ---------------- fp32 small path ----------------

__global__ void ops_k(const float* __restrict__ ld, const float* __restrict__ lf,
                      const float* __restrict__ lawre, const float* __restrict__ lawim,
                      const float* __restrict__ dtp,
                      float* __restrict__ odr, float* __restrict__ odi,
                      float* __restrict__ ofr, float* __restrict__ ofi) {
  int d = blockIdx.x * 256 + threadIdx.x;
  float dt = dtp[0];
  float lre = -expf(ld[d]) + lawre[d];
  float lim = lf[d] + lawim[d];
  float Lre = -log1pf(expf(-lre));
  float zr = Lre * dt, zi = lim * dt;
  float er = expf(zr);
  float Odr = er * cosf(zi), Odi = er * sinf(zi);
  float m2 = zr * zr + zi * zi;
  float p1r, p1i;
  if (sqrtf(m2) < 1e-4f) {
    p1r = 1.f + 0.5f * zr + (zr * zr - zi * zi) * (1.f / 6.f);
    p1i = 0.5f * zi + (2.f * zr * zi) * (1.f / 6.f);
  } else {
    float nr = Odr - 1.f, ni = Odi, inv = 1.f / m2;
    p1r = (nr * zr + ni * zi) * inv;
    p1i = (ni * zr - nr * zi) * inv;
  }
  odr[d] = Odr; odi[d] = Odi;
  ofr[d] = p1r * dt; ofi[d] = p1i * dt;
}

// wave-per-output MLP: out[b][o] = cat(in0,in1)[b] . W[o] + bias[o]
template <bool SPLIT>
__global__ void mlpw_k(const float* __restrict__ in0, const float* __restrict__ in1,
                       const float* __restrict__ W, const float* __restrict__ bias,
                       float* __restrict__ out0, float* __restrict__ out1) {
  int wid = blockIdx.x * 4 + (threadIdx.x >> 6);
  int lane = threadIdx.x & 63;
  int b = wid >> 11, o = wid & 2047;
  const float* w0 = W + (size_t)o * 2048;
  float acc = 0.f;
  for (int c = lane; c < Dn; c += 64)
    acc += in0[b * Dn + c] * w0[c] + in1[b * Dn + c] * w0[Dn + c];
  for (int s = 32; s; s >>= 1) acc += __shfl_xor(acc, s);
  if (lane == 0) {
    acc += bias[o];
    if (SPLIT) {
      if (o < Dn) out0[b * Dn + o] = acc;
      else        out1[b * Dn + (o - Dn)] = acc;
    } else out0[b * 2048 + o] = acc;
  }
}

__global__ void flux_k(const float* __restrict__ fre, const float* __restrict__ fim,
                       const float* __restrict__ dre, const float* __restrict__ dim_,
                       const float* __restrict__ xm,
                       float* __restrict__ fnre, float* __restrict__ fnim,
                       float* __restrict__ outf) {
  int t = blockIdx.x * 256 + threadIdx.x;
  int b = t >> 10, d = t & 1023;
  float dr = 1.f / (1.f + expf(-dre[d]));
  float di = dim_[d];
  float fr = fre[t], fi = fim[t];
  float xr = xm[b * 2048 + d], xi = xm[b * 2048 + Dn + d];
  float nr = fr * dr - fi * di + xr;
  float ni = fr * di + fi * dr + xi;
  fnre[t] = nr; fnim[t] = ni;
  outf[OUT1 + t] = nr;
  outf[OUT1 + Bn * Dn + t] = ni;
}

__global__ void srcf_k(const float* __restrict__ sre, const float* __restrict__ sim,
                       const float* __restrict__ ofr, const float* __restrict__ ofi,
                       float* __restrict__ tre, float* __restrict__ tim) {
  int t = blockIdx.x * 256 + threadIdx.x;
  int d = t & 1023;
  float sr = sre[t], si = sim[t], fr = ofr[d], fi = ofi[d];
  tre[t] = sr * fr - si * fi;
  tim[t] = sr * fi + si * fr;
}

// ---------------- MFMA complex GEMM ----------------
// C[M][N] = sum_k X[m][k]*Y[k][n]; Y read from SY stored [N][K] (SY = Y^T).
// X: single planes (re, im). Y: single (YS=1, planes re/im) or split (YS=0,
// planes rh, rl, ih, il). YNEG: 0 none, 1 conj (negate im), 2 -conj (negate re).
// OUT: 0 split4 planes, 1 single2 planes, 2 fp32 re/im.
struct MGP {
  const short* X[2][2];
  const short* X2p[2][2];   // second X set (k >= Kx) when X2
  const short* Y[2][4];
  short* O[2][4];
  float* OF[2][2];
  const float* S[2][2];
  int M, K, N, Kx;
};

template <int MI, int NI, int YS, int X2, int ADDX, int SRC, int OUT, int YNEG>
__launch_bounds__(256, 2)
__global__ void mgemm_k(MGP g) {
  constexpr int BM = MI * 32, BN = NI * 32;
  constexpr int NPY = YS ? 2 : 4;
  __shared__ __align__(16) short As[2][BM * 32];
  __shared__ __align__(16) short Bs[NPY][BN * 32];
  const int tid = threadIdx.x;
  const int lane = tid & 63, wave = tid >> 6;
  const int wm = wave >> 1, wn = wave & 1;
  const int bz = blockIdx.z;
  const int row0 = blockIdx.y * BM, col0 = blockIdx.x * BN;
  const int fl = lane & 15, fq = lane >> 4;
  const int K = g.K, N = g.N, Kx = g.Kx;
  const int srow = lane >> 2;
  const int schunk = (lane & 3) * 8;

  s8v sgn;
  #pragma unroll
  for (int i = 0; i < 8; i++) sgn[i] = (short)0x8000;

  f4v aR[MI][NI], aI[MI][NI];
  #pragma unroll
  for (int m = 0; m < MI; m++)
    #pragma unroll
    for (int n = 0; n < NI; n++)
      #pragma unroll
      for (int r = 0; r < 4; r++) { aR[m][n][r] = 0.f; aI[m][n][r] = 0.f; }

  for (int k0 = 0; k0 < K; k0 += 32) {
    // ---- stage X planes (global -> LDS, 16B/lane, wave-uniform LDS base) ----
    const short* const* xset = g.X[bz];
    int kk = k0;
    if (X2) { if (k0 >= Kx) { xset = g.X2p[bz]; kk = k0 - Kx; } }
    #pragma unroll
    for (int p = 0; p < 2; p++)
      #pragma unroll
      for (int u = 0; u < BM / 64; u++) {
        int r = wave * (BM / 4) + u * 16 + srow;
        const short* gp = xset[p] + (size_t)(row0 + r) * Kx + kk + schunk;
        short* lp = &As[p][(wave * (BM / 4) + u * 16) * 32];
        __builtin_amdgcn_global_load_lds((const __attribute__((address_space(1))) void*)gp,
                                         (__attribute__((address_space(3))) void*)lp, 16, 0, 0);
      }
    // ---- stage Y planes ----
    #pragma unroll
    for (int p = 0; p < NPY; p++)
      #pragma unroll
      for (int u = 0; u < BN / 64; u++) {
        int r = wave * (BN / 4) + u * 16 + srow;
        const short* gp = g.Y[bz][p] + (size_t)(col0 + r) * K + k0 + schunk;
        short* lp = &Bs[p][(wave * (BN / 4) + u * 16) * 32];
        __builtin_amdgcn_global_load_lds((const __attribute__((address_space(1))) void*)gp,
                                         (__attribute__((address_space(3))) void*)lp, 16, 0, 0);
      }
    __syncthreads();

    // ---- B fragments (B[k][n]: n = lane&15, k = (lane>>4)*8 + j) ----
    s8v bf[NI][NPY];
    #pragma unroll
    for (int n = 0; n < NI; n++)
      #pragma unroll
      for (int p = 0; p < NPY; p++)
        bf[n][p] = *(const s8v*)&Bs[p][(wn * NI * 16 + n * 16 + fl) * 32 + fq * 8];
    if constexpr (YNEG == 1) {     // conj: negate im planes
      #pragma unroll
      for (int n = 0; n < NI; n++) {
        if constexpr (YS) bf[n][1] ^= sgn;
        else { bf[n][2] ^= sgn; bf[n][3] ^= sgn; }
      }
    } else if constexpr (YNEG == 2) {  // -conj: negate re planes
      #pragma unroll
      for (int n = 0; n < NI; n++) {
        if constexpr (YS) bf[n][0] ^= sgn;
        else { bf[n][0] ^= sgn; bf[n][1] ^= sgn; }
      }
    }

    // ---- compute ----
    #pragma unroll
    for (int m = 0; m < MI; m++) {
      int arow = (wm * MI * 16 + m * 16 + fl) * 32 + fq * 8;
      s8v arh = *(const s8v*)&As[0][arow];
      s8v aih = *(const s8v*)&As[1][arow];
      s8v nih = aih ^ sgn;
      #pragma unroll
      for (int n = 0; n < NI; n++) {
        f4v cr = aR[m][n], ci = aI[m][n];
        if constexpr (YS) {
          cr = MFMA(arh, bf[n][0], cr); cr = MFMA(nih, bf[n][1], cr);
          ci = MFMA(arh, bf[n][1], ci); ci = MFMA(aih, bf[n][0], ci);
        } else {
          cr = MFMA(arh, bf[n][0], cr); cr = MFMA(arh, bf[n][1], cr);
          cr = MFMA(nih, bf[n][2], cr); cr = MFMA(nih, bf[n][3], cr);
          ci = MFMA(arh, bf[n][2], ci); ci = MFMA(arh, bf[n][3], ci);
          ci = MFMA(aih, bf[n][0], ci); ci = MFMA(aih, bf[n][1], ci);
        }
        aR[m][n] = cr; aI[m][n] = ci;
      }
    }
    __syncthreads();
  }

  // ---- epilogue: C/D layout col = lane&15, row = (lane>>4)*4 + reg ----
  #pragma unroll
  for (int m = 0; m < MI; m++) {
    #pragma unroll
    for (int n = 0; n < NI; n++) {
      int grb = row0 + wm * MI * 16 + m * 16 + fq * 4;
      int gc  = col0 + wn * NI * 16 + n * 16 + fl;
      #pragma unroll
      for (int r = 0; r < 4; r++) {
        int gr = grb + r;
        size_t gi = (size_t)gr * N + gc;
        float vr = aR[m][n][r], vi = aI[m][n][r];
        if constexpr (ADDX) {
          vr += bf2f(g.X[bz][0][gi]);
          vi += bf2f(g.X[bz][1][gi]);
        }
        if constexpr (SRC) {
          int sb = gr >> 8;
          vr += g.S[bz][0][sb * Dn + gc];
          vi += g.S[bz][1][sb * Dn + gc];
        }
        if constexpr (OUT == 0) {
          short h, l;
          split2(vr, h, l); g.O[bz][0][gi] = h; g.O[bz][1][gi] = l;
          split2(vi, h, l); g.O[bz][2][gi] = h; g.O[bz][3][gi] = l;
        } else if constexpr (OUT == 1) {
          g.O[bz][0][gi] = f2bf(vr);
          g.O[bz][1][gi] = f2bf(vi);
        } else {
          g.OF[bz][0][gi] = vr;
          g.OF[bz][1][gi] = vi;
        }
      }
    }
  }
}

// ---------------- host ----------------

extern "C" void kernel_launch(void* const* d_in, const int* in_sizes, int n_in,
                              void* d_out, int out_size, void* d_ws, size_t ws_size,
                              hipStream_t stream) {
  (void)in_sizes; (void)n_in; (void)out_size; (void)ws_size;
  const float* h_re  = (const float*)d_in[0];
  const float* h_im  = (const float*)d_in[1];
  const float* x_re  = (const float*)d_in[2];
  const float* x_im  = (const float*)d_in[3];
  const float* xg_re = (const float*)d_in[4];
  const float* xg_im = (const float*)d_in[5];
  const float* fl_re = (const float*)d_in[6];
  const float* fl_im = (const float*)d_in[7];
  const float* dtp   = (const float*)d_in[8];
  const float* u_rre = (const float*)d_in[9];
  const float* u_rim = (const float*)d_in[10];
  const float* v_rre = (const float*)d_in[11];
  const float* v_rim = (const float*)d_in[12];
  const float* lsig  = (const float*)d_in[13];
  const float* dcre  = (const float*)d_in[14];
  const float* dcim  = (const float*)d_in[15];
  const float* mixw  = (const float*)d_in[16];
  const float* mixb  = (const float*)d_in[17];
  const float* projw = (const float*)d_in[18];
  const float* projb = (const float*)d_in[19];
  const float* ld_   = (const float*)d_in[20];
  const float* lf_   = (const float*)d_in[21];
  const float* lawre = (const float*)d_in[22];
  const float* lawim = (const float*)d_in[23];
  float* outf = (float*)d_out;

  short* wsS = (short*)d_ws;
  auto pl = [&](int i) { return wsS + (size_t)i * DD; };
  // plane map (1 unit = 1024x1024 bf16 = 2MB):
  //  0-1 A_u (later XscV)   2-3 A_v (later XscU)
  //  4-5 P0_u, 6-7 P0_v     (later Minv split 4-7)
  //  8-9 P1_u, 10-11 P1_v   (later M split 8-11)
  // 12-13 Tb0_u, 14-15 Tb0_v  \__ later W1 split [1024][2048]: planes at 12,14,16,18
  // 16-17 Tb1_u, 18-19 Tb1_v  /
  // 20-21 U, 22-23 V          (later hp: rh 20-23, ih 24-27)
  // 28-35 xp (rh 28-31, ih 32-35); 36-43 ht (rh 36-39, ih 40-43)
  float* fbase = (float*)(wsS + (size_t)44 * DD);
  float* xm   = fbase;
  float* fnre = xm + 32768;
  float* fnim = fnre + 16384;
  float* sre  = fnim + 16384;
  float* sim  = sre + 16384;
  float* sfre = sim + 16384;
  float* sfim = sfre + 16384;
  float* odr  = sfim + 16384;
  float* odi  = odr + Dn;
  float* ofr  = odi + Dn;
  float* ofi  = ofr + Dn;

  const dim3 blk(256);
  const dim3 gDD(16, 16, 2);

  auto set2  = [&](const short** f, int u) { f[0] = pl(u); f[1] = pl(u + 1); };
  auto set2o = [&](short** f, int u) { f[0] = pl(u); f[1] = pl(u + 1); };
  auto set4o = [&](short** f, int u) { for (int i = 0; i < 4; i++) f[i] = pl(u + i); };

  // ---- build A (single planes) ----
  build_A2_k<<<4096, blk, 0, stream>>>(u_rre, u_rim, pl(0), pl(1));
  build_A2_k<<<4096, blk, 0, stream>>>(v_rre, v_rim, pl(2), pl(3));

  // A2 = A @ A (Y = A, SY = -conj(A) -> YNEG=2) -> P0
  {
    MGP G{};
    set2(G.X[0], 0); set2(G.X[1], 2);
    set2(G.Y[0], 0); set2(G.Y[1], 2);
    set2o(G.O[0], 4); set2o(G.O[1], 6);
    G.M = G.K = G.N = G.Kx = 1024;
    mgemm_k<2,2,1,0,0,0,1,2><<<gDD, blk, 0, stream>>>(G);
  }
  // T0 = I + 2A + A2
  t02_k<<<4096, blk, 0, stream>>>(pl(0), pl(1), pl(4), pl(5), pl(12), pl(13));
  t02_k<<<4096, blk, 0, stream>>>(pl(2), pl(3), pl(6), pl(7), pl(14), pl(15));

  auto chain_pow = [&](int xu, int xv, int ou, int ov) {  // P' = P@P (Herm -> conj)
    MGP G{};
    set2(G.X[0], xu); set2(G.X[1], xv);
    set2(G.Y[0], xu); set2(G.Y[1], xv);
    set2o(G.O[0], ou); set2o(G.O[1], ov);
    G.M = G.K = G.N = G.Kx = 1024;
    mgemm_k<2,2,1,0,0,0,1,1><<<gDD, blk, 0, stream>>>(G);
  };
  auto chain_t = [&](int xu, int xv, int yu, int yv, int ou, int ov) {  // T' = T + T@P
    MGP G{};
    set2(G.X[0], xu); set2(G.X[1], xv);
    set2(G.Y[0], yu); set2(G.Y[1], yv);
    set2o(G.O[0], ou); set2o(G.O[1], ov);
    G.M = G.K = G.N = G.Kx = 1024;
    mgemm_k<2,2,1,0,1,0,1,1><<<gDD, blk, 0, stream>>>(G);
  };
  chain_pow(4, 6, 8, 10);             // A4  = A2*A2   -> P1
  chain_t(12, 14, 4, 6, 16, 18);      // T1  = T0(I+A2)  -> Tb1
  chain_pow(8, 10, 4, 6);             // A8  = A4*A4   -> P0
  chain_t(16, 18, 8, 10, 12, 14);     // T2  = T1(I+A4)  -> Tb0
  chain_pow(4, 6, 8, 10);             // A16 = A8*A8   -> P1
  chain_t(12, 14, 4, 6, 16, 18);      // T3  = T2(I+A8)  -> Tb1
  chain_t(16, 18, 8, 10, 20, 22);     // T4  = T3(I+A16) -> U(20-21) / V(22-23)

  // ---- fp32 small path ----
  ops_k<<<4, blk, 0, stream>>>(ld_, lf_, lawre, lawim, dtp, odr, odi, ofr, ofi);
  mlpw_k<false><<<8192, blk, 0, stream>>>(xg_re, xg_im, mixw, mixb, xm, nullptr);
  flux_k<<<64, blk, 0, stream>>>(fl_re, fl_im, dcre, dcim, xm, fnre, fnim, outf);
  mlpw_k<true><<<8192, blk, 0, stream>>>(fnre, fnim, projw, projb, sre, sim);
  srcf_k<<<64, blk, 0, stream>>>(sre, sim, ofr, ofi, sfre, sfim);

  // ---- Minv = (V s^-1) conj(U)^T ; M = (U s) conj(V)^T  (batched, split out) ----
  colscale2_k<<<4096, blk, 0, stream>>>(pl(22), pl(23), lsig, -1.f, pl(0), pl(1)); // XscV
  colscale2_k<<<4096, blk, 0, stream>>>(pl(20), pl(21), lsig, +1.f, pl(2), pl(3)); // XscU
  {
    MGP G{};
    set2(G.X[0], 0); set2(G.X[1], 2);
    set2(G.Y[0], 20); set2(G.Y[1], 22);   // conj via YNEG=1
    set4o(G.O[0], 4); set4o(G.O[1], 8);   // Minv -> 4-7 split, M -> 8-11 split
    G.M = G.K = G.N = G.Kx = 1024;
    mgemm_k<2,2,1,0,0,0,0,1><<<gDD, blk, 0, stream>>>(G);
  }
  // W1 split [1024][2048] = [Minv*od | Minv*of] at planes 12,14,16,18
  w1build_k<<<4096, blk, 0, stream>>>(pl(4), pl(5), pl(6), pl(7), odr, odi, ofr, ofi,
                                      pl(12), pl(14), pl(16), pl(18));
  // h, x -> single-bf16 planes
  conv2_k<<<16384, blk, 0, stream>>>(h_re, h_im, pl(20), pl(24));
  conv2_k<<<16384, blk, 0, stream>>>(x_re, x_im, pl(28), pl(32));

  // ---- big GEMM 1: ht = [h|x] @ [W1d;W1f] + srcf -> single-bf16 ht ----
  {
    MGP G{};
    G.X[0][0] = pl(20); G.X[0][1] = pl(24);
    G.X2p[0][0] = pl(28); G.X2p[0][1] = pl(32);
    G.Y[0][0] = pl(12); G.Y[0][1] = pl(14); G.Y[0][2] = pl(16); G.Y[0][3] = pl(18);
    G.O[0][0] = pl(36); G.O[0][1] = pl(40);
    G.S[0][0] = sfre; G.S[0][1] = sfim;
    G.M = 4096; G.K = 2048; G.N = 1024; G.Kx = 1024;
    mgemm_k<4,2,0,1,0,1,1,0><<<dim3(16, 32, 1), blk, 0, stream>>>(G);
  }
  // ---- big GEMM 2: out = ht @ M^T -> fp32 d_out ----
  {
    MGP G{};
    G.X[0][0] = pl(36); G.X[0][1] = pl(40);
    G.Y[0][0] = pl(8); G.Y[0][1] = pl(9); G.Y[0][2] = pl(10); G.Y[0][3] = pl(11);
    G.OF[0][0] = outf; G.OF[0][1] = outf + TBD;
    G.M = 4096; G.K = 1024; G.N = 1024; G.Kx = 1024;
    mgemm_k<4,2,0,0,0,0,2,0><<<dim3(16, 32, 1), blk, 0, stream>>>(G);
  }
}

// Round 5
// 741.378 us; speedup vs baseline: 11.0705x; 1.0215x over previous
//
#include <hip/hip_runtime.h>

// TemporalPropagator on MI355X — bf16-MFMA, round 5.
// Cayley telescoping: (I-A)^-1(I+A) = (I+A)^2 (I+A^2)(I+A^4)(I+A^8)(I+A^16).
// All GEMMs single-bf16 x single-bf16 (4 MFMA / complex MAC).
// New this round: SYRK-triangular pow GEMMs (Hermitian P^2 = P P^H, upper
// tiles + exact conj-mirror); KS=2 (BK=64, two k-chunks per barrier);
// Minv/M/W1 stored single-bf16 (incoherent quant error ~0.01 absmax).

using s8v = __attribute__((ext_vector_type(8))) short;
using f4v = __attribute__((ext_vector_type(4))) float;

constexpr int Dn = 1024, TBn = 4096, Bn = 16;
constexpr size_t DD  = (size_t)Dn * Dn;
constexpr size_t TBD = (size_t)TBn * Dn;
constexpr int OUT1 = 2 * TBn * Dn;

#define MFMA(a, b, c) __builtin_amdgcn_mfma_f32_16x16x32_bf16(a, b, c, 0, 0, 0)

__device__ __forceinline__ short f2bf(float v) {
  unsigned u = __float_as_uint(v);
  return (short)((u + 0x7fffu + ((u >> 16) & 1u)) >> 16);
}
__device__ __forceinline__ float bf2f(short s) {
  return __uint_as_float(((unsigned)(unsigned short)s) << 16);
}

// ---------------- elementwise producers ----------------

__global__ void build_A2_k(const float* __restrict__ rre, const float* __restrict__ rim,
                           short* __restrict__ o0, short* __restrict__ o1) {
  int idx = blockIdx.x * 256 + threadIdx.x;
  int i = idx >> 10, j = idx & 1023;
  o0[idx] = f2bf(0.5f * (rre[idx] - rre[j * Dn + i]));
  o1[idx] = f2bf(0.5f * (rim[idx] + rim[j * Dn + i]));
}

__global__ void t02_k(const short* __restrict__ a0, const short* __restrict__ a1,
                      const short* __restrict__ p0, const short* __restrict__ p1,
                      short* __restrict__ o0, short* __restrict__ o1) {
  int idx = blockIdx.x * 256 + threadIdx.x;
  int i = idx >> 10, j = idx & 1023;
  o0[idx] = f2bf((i == j ? 1.f : 0.f) + 2.f * bf2f(a0[idx]) + bf2f(p0[idx]));
  o1[idx] = f2bf(2.f * bf2f(a1[idx]) + bf2f(p1[idx]));
}

// Hermitian mirror: fill lower triangle with conj of upper (2 matrices)
__global__ void mirror_k(short* __restrict__ r0, short* __restrict__ i0,
                         short* __restrict__ r1, short* __restrict__ i1) {
  int idx = blockIdx.x * 256 + threadIdx.x;   // 2 * 1M
  int z = idx >> 20, rem = idx & ((1 << 20) - 1);
  int i = rem >> 10, j = rem & 1023;
  if (j <= i) return;
  short* rp = z ? r1 : r0;
  short* ip = z ? i1 : i0;
  rp[j * Dn + i] = rp[i * Dn + j];
  ip[j * Dn + i] = (short)(ip[i * Dn + j] ^ (short)0x8000);
}

__global__ void colscale2_k(const short* __restrict__ u0, const short* __restrict__ u1,
                            const float* __restrict__ ls, float sgn,
                            short* __restrict__ o0, short* __restrict__ o1) {
  int idx = blockIdx.x * 256 + threadIdx.x;
  int j = idx & 1023;
  float sv = expf(sgn * ls[j]);
  o0[idx] = f2bf(bf2f(u0[idx]) * sv);
  o1[idx] = f2bf(bf2f(u1[idx]) * sv);
}

// W1[n][k] = Minv[n][k]*op_decay[n]; W1[n][1024+k] = Minv[n][k]*op_forcing[n]
__global__ void w1build_k(const short* __restrict__ m0, const short* __restrict__ m1,
                          const float* __restrict__ odr, const float* __restrict__ odi,
                          const float* __restrict__ ofr, const float* __restrict__ ofi,
                          short* __restrict__ w0, short* __restrict__ w1) {
  int idx = blockIdx.x * 256 + threadIdx.x;
  int n = idx >> 10, k = idx & 1023;
  float vr = bf2f(m0[idx]), vi = bf2f(m1[idx]);
  size_t d0 = (size_t)n * 2048 + k, d1 = d0 + 1024;
  float dr = odr[n], di = odi[n], fr = ofr[n], fi = ofi[n];
  w0[d0] = f2bf(vr * dr - vi * di);
  w1[d0] = f2bf(vr * di + vi * dr);
  w0[d1] = f2bf(vr * fr - vi * fi);
  w1[d1] = f2bf(vr * fi + vi * fr);
}

__global__ void conv2_k(const float* __restrict__ re, const float* __restrict__ im,
                        short* __restrict__ orh, short* __restrict__ oih) {
  int idx = blockIdx.x * 256 + threadIdx.x;
  orh[idx] = f2bf(re[idx]);
  oih[idx] = f2bf(im[idx]);
}

// ---------------- fp32 small path ----------------

__global__ void ops_k(const float* __restrict__ ld, const float* __restrict__ lf,
                      const float* __restrict__ lawre, const float* __restrict__ lawim,
                      const float* __restrict__ dtp,
                      float* __restrict__ odr, float* __restrict__ odi,
                      float* __restrict__ ofr, float* __restrict__ ofi) {
  int d = blockIdx.x * 256 + threadIdx.x;
  float dt = dtp[0];
  float lre = -expf(ld[d]) + lawre[d];
  float lim = lf[d] + lawim[d];
  float Lre = -log1pf(expf(-lre));
  float zr = Lre * dt, zi = lim * dt;
  float er = expf(zr);
  float Odr = er * cosf(zi), Odi = er * sinf(zi);
  float m2 = zr * zr + zi * zi;
  float p1r, p1i;
  if (sqrtf(m2) < 1e-4f) {
    p1r = 1.f + 0.5f * zr + (zr * zr - zi * zi) * (1.f / 6.f);
    p1i = 0.5f * zi + (2.f * zr * zi) * (1.f / 6.f);
  } else {
    float nr = Odr - 1.f, ni = Odi, inv = 1.f / m2;
    p1r = (nr * zr + ni * zi) * inv;
    p1i = (ni * zr - nr * zi) * inv;
  }
  odr[d] = Odr; odi[d] = Odi;
  ofr[d] = p1r * dt; ofi[d] = p1i * dt;
}

template <bool SPLIT>
__global__ void mlpw_k(const float* __restrict__ in0, const float* __restrict__ in1,
                       const float* __restrict__ W, const float* __restrict__ bias,
                       float* __restrict__ out0, float* __restrict__ out1) {
  int wid = blockIdx.x * 4 + (threadIdx.x >> 6);
  int lane = threadIdx.x & 63;
  int b = wid >> 11, o = wid & 2047;
  const float* w0 = W + (size_t)o * 2048;
  float acc = 0.f;
  for (int c = lane; c < Dn; c += 64)
    acc += in0[b * Dn + c] * w0[c] + in1[b * Dn + c] * w0[Dn + c];
  for (int s = 32; s; s >>= 1) acc += __shfl_xor(acc, s);
  if (lane == 0) {
    acc += bias[o];
    if (SPLIT) {
      if (o < Dn) out0[b * Dn + o] = acc;
      else        out1[b * Dn + (o - Dn)] = acc;
    } else out0[b * 2048 + o] = acc;
  }
}

__global__ void flux_k(const float* __restrict__ fre, const float* __restrict__ fim,
                       const float* __restrict__ dre, const float* __restrict__ dim_,
                       const float* __restrict__ xm,
                       float* __restrict__ fnre, float* __restrict__ fnim,
                       float* __restrict__ outf) {
  int t = blockIdx.x * 256 + threadIdx.x;
  int b = t >> 10, d = t & 1023;
  float dr = 1.f / (1.f + expf(-dre[d]));
  float di = dim_[d];
  float fr = fre[t], fi = fim[t];
  float xr = xm[b * 2048 + d], xi = xm[b * 2048 + Dn + d];
  float nr = fr * dr - fi * di + xr;
  float ni = fr * di + fi * dr + xi;
  fnre[t] = nr; fnim[t] = ni;
  outf[OUT1 + t] = nr;
  outf[OUT1 + Bn * Dn + t] = ni;
}

__global__ void srcf_k(const float* __restrict__ sre, const float* __restrict__ sim,
                       const float* __restrict__ ofr, const float* __restrict__ ofi,
                       float* __restrict__ tre, float* __restrict__ tim) {
  int t = blockIdx.x * 256 + threadIdx.x;
  int d = t & 1023;
  float sr = sre[t], si = sim[t], fr = ofr[d], fi = ofi[d];
  tre[t] = sr * fr - si * fi;
  tim[t] = sr * fi + si * fr;
}

// ---------------- MFMA complex GEMM ----------------
// C[M][N] = sum_k X[m][k]*Y[k][n]; Y read from SY stored [N][K] (SY = Y^T).
// X, Y single bf16 planes (re, im). YNEG: 0 none, 1 conj, 2 -conj.
// TRI: triangular grid (upper tiles only, square, BM==BN).
// KS: k-chunks (of 32) per barrier. OUT: 1 single2 planes, 2 fp32 re/im.
struct MGP {
  const short* X[2][2];
  const short* X2p[2][2];
  const short* Y[2][2];
  short* O[2][2];
  float* OF[2][2];
  const float* S[2][2];
  int M, K, N, Kx;
};

template <int MI, int NI, int KS, int TRI, int X2, int ADDX, int SRC, int OUT, int YNEG>
__launch_bounds__(256, 2)
__global__ void mgemm_k(MGP g) {
  constexpr int BM = MI * 32, BN = NI * 32;
  __shared__ __align__(16) short As[2][KS * BM * 32];
  __shared__ __align__(16) short Bs[2][KS * BN * 32];
  const int tid = threadIdx.x;
  const int lane = tid & 63, wave = tid >> 6;
  const int wm = wave >> 1, wn = wave & 1;
  const int bz = blockIdx.z;
  const int fl = lane & 15, fq = lane >> 4;
  const int K = g.K, N = g.N, Kx = g.Kx;
  const int srow = lane >> 2;
  const int schunk = (lane & 3) * 8;

  int row0, col0;
  if constexpr (TRI) {
    int t = blockIdx.x, r = 0;
    const int gt = N / BN;
    while (t >= gt - r) { t -= gt - r; r++; }
    row0 = r * BM; col0 = (r + t) * BN;
  } else {
    row0 = blockIdx.y * BM; col0 = blockIdx.x * BN;
  }

  s8v sgn;
  #pragma unroll
  for (int i = 0; i < 8; i++) sgn[i] = (short)0x8000;

  f4v aR[MI][NI], aI[MI][NI];
  #pragma unroll
  for (int m = 0; m < MI; m++)
    #pragma unroll
    for (int n = 0; n < NI; n++)
      #pragma unroll
      for (int r = 0; r < 4; r++) { aR[m][n][r] = 0.f; aI[m][n][r] = 0.f; }

  for (int k0 = 0; k0 < K; k0 += 32 * KS) {
    // ---- stage X/Y planes (global -> LDS, 16B/lane, wave-uniform base) ----
    #pragma unroll
    for (int c = 0; c < KS; c++) {
      int kc = k0 + c * 32;
      const short* const* xs = g.X[bz];
      int kk = kc;
      if constexpr (X2) { if (kc >= Kx) { xs = g.X2p[bz]; kk = kc - Kx; } }
      #pragma unroll
      for (int p = 0; p < 2; p++)
        #pragma unroll
        for (int u = 0; u < BM / 64; u++) {
          int r = wave * (BM / 4) + u * 16 + srow;
          const short* gp = xs[p] + (size_t)(row0 + r) * Kx + kk + schunk;
          short* lp = &As[p][c * BM * 32 + (wave * (BM / 4) + u * 16) * 32];
          __builtin_amdgcn_global_load_lds((const __attribute__((address_space(1))) void*)gp,
                                           (__attribute__((address_space(3))) void*)lp, 16, 0, 0);
        }
      #pragma unroll
      for (int p = 0; p < 2; p++)
        #pragma unroll
        for (int u = 0; u < BN / 64; u++) {
          int r = wave * (BN / 4) + u * 16 + srow;
          const short* gp = g.Y[bz][p] + (size_t)(col0 + r) * K + kc + schunk;
          short* lp = &Bs[p][c * BN * 32 + (wave * (BN / 4) + u * 16) * 32];
          __builtin_amdgcn_global_load_lds((const __attribute__((address_space(1))) void*)gp,
                                           (__attribute__((address_space(3))) void*)lp, 16, 0, 0);
        }
    }
    __syncthreads();

    #pragma unroll
    for (int c = 0; c < KS; c++) {
      // B fragments (B[k][n]: n = lane&15, k = (lane>>4)*8 + j)
      s8v bf[NI][2];
      #pragma unroll
      for (int n = 0; n < NI; n++)
        #pragma unroll
        for (int p = 0; p < 2; p++)
          bf[n][p] = *(const s8v*)&Bs[p][c * BN * 32 + (wn * NI * 16 + n * 16 + fl) * 32 + fq * 8];
      if constexpr (YNEG == 1) {
        #pragma unroll
        for (int n = 0; n < NI; n++) bf[n][1] ^= sgn;
      } else if constexpr (YNEG == 2) {
        #pragma unroll
        for (int n = 0; n < NI; n++) bf[n][0] ^= sgn;
      }
      #pragma unroll
      for (int m = 0; m < MI; m++) {
        int arow = c * BM * 32 + (wm * MI * 16 + m * 16 + fl) * 32 + fq * 8;
        s8v arh = *(const s8v*)&As[0][arow];
        s8v aih = *(const s8v*)&As[1][arow];
        s8v nih = aih ^ sgn;
        #pragma unroll
        for (int n = 0; n < NI; n++) {
          f4v cr = aR[m][n], ci = aI[m][n];
          cr = MFMA(arh, bf[n][0], cr); cr = MFMA(nih, bf[n][1], cr);
          ci = MFMA(arh, bf[n][1], ci); ci = MFMA(aih, bf[n][0], ci);
          aR[m][n] = cr; aI[m][n] = ci;
        }
      }
    }
    __syncthreads();
  }

  // ---- epilogue: C/D layout col = lane&15, row = (lane>>4)*4 + reg ----
  #pragma unroll
  for (int m = 0; m < MI; m++) {
    #pragma unroll
    for (int n = 0; n < NI; n++) {
      int grb = row0 + wm * MI * 16 + m * 16 + fq * 4;
      int gc  = col0 + wn * NI * 16 + n * 16 + fl;
      #pragma unroll
      for (int r = 0; r < 4; r++) {
        int gr = grb + r;
        size_t gi = (size_t)gr * N + gc;
        float vr = aR[m][n][r], vi = aI[m][n][r];
        if constexpr (ADDX) {
          vr += bf2f(g.X[bz][0][gi]);
          vi += bf2f(g.X[bz][1][gi]);
        }
        if constexpr (SRC) {
          int sb = gr >> 8;
          vr += g.S[bz][0][sb * Dn + gc];
          vi += g.S[bz][1][sb * Dn + gc];
        }
        if constexpr (OUT == 1) {
          g.O[bz][0][gi] = f2bf(vr);
          g.O[bz][1][gi] = f2bf(vi);
        } else {
          g.OF[bz][0][gi] = vr;
          g.OF[bz][1][gi] = vi;
        }
      }
    }
  }
}

// ---------------- host ----------------

extern "C" void kernel_launch(void* const* d_in, const int* in_sizes, int n_in,
                              void* d_out, int out_size, void* d_ws, size_t ws_size,
                              hipStream_t stream) {
  (void)in_sizes; (void)n_in; (void)out_size; (void)ws_size;
  const float* h_re  = (const float*)d_in[0];
  const float* h_im  = (const float*)d_in[1];
  const float* x_re  = (const float*)d_in[2];
  const float* x_im  = (const float*)d_in[3];
  const float* xg_re = (const float*)d_in[4];
  const float* xg_im = (const float*)d_in[5];
  const float* fl_re = (const float*)d_in[6];
  const float* fl_im = (const float*)d_in[7];
  const float* dtp   = (const float*)d_in[8];
  const float* u_rre = (const float*)d_in[9];
  const float* u_rim = (const float*)d_in[10];
  const float* v_rre = (const float*)d_in[11];
  const float* v_rim = (const float*)d_in[12];
  const float* lsig  = (const float*)d_in[13];
  const float* dcre  = (const float*)d_in[14];
  const float* dcim  = (const float*)d_in[15];
  const float* mixw  = (const float*)d_in[16];
  const float* mixb  = (const float*)d_in[17];
  const float* projw = (const float*)d_in[18];
  const float* projb = (const float*)d_in[19];
  const float* ld_   = (const float*)d_in[20];
  const float* lf_   = (const float*)d_in[21];
  const float* lawre = (const float*)d_in[22];
  const float* lawim = (const float*)d_in[23];
  float* outf = (float*)d_out;

  short* wsS = (short*)d_ws;
  auto pl = [&](int i) { return wsS + (size_t)i * DD; };
  // plane map (unit = 1024x1024 bf16 = 2MB):
  //  0-1 A_u / XscV    2-3 A_v / XscU
  //  4-5 P0_u / Minv   6-7 P0_v / M
  //  8-9 P1_u \ later W1 [1024][2048]: re 8-9, im 10-11
  // 10-11 P1_v /
  // 12-13 Tb0_u, 14-15 Tb0_v \ later hp: re 12-15, im 16-19
  // 16-17 Tb1_u, 18-19 Tb1_v /
  // 20-21 U, 22-23 V          later xp: re 20-23, im 24-27
  // 28-35 ht (re 28-31, im 32-35)
  float* fbase = (float*)(wsS + (size_t)36 * DD);
  float* xm   = fbase;
  float* fnre = xm + 32768;
  float* fnim = fnre + 16384;
  float* sre  = fnim + 16384;
  float* sim  = sre + 16384;
  float* sfre = sim + 16384;
  float* sfim = sfre + 16384;
  float* odr  = sfim + 16384;
  float* odi  = odr + Dn;
  float* ofr  = odi + Dn;
  float* ofi  = ofr + Dn;

  const dim3 blk(256);
  const dim3 gTRI(136, 1, 2);   // 16*17/2 upper tiles, z = {U,V}
  const dim3 gFULL(16, 16, 2);

  auto set2  = [&](const short** f, int u) { f[0] = pl(u); f[1] = pl(u + 1); };
  auto set2o = [&](short** f, int u) { f[0] = pl(u); f[1] = pl(u + 1); };

  // ---- build A ----
  build_A2_k<<<4096, blk, 0, stream>>>(u_rre, u_rim, pl(0), pl(1));
  build_A2_k<<<4096, blk, 0, stream>>>(v_rre, v_rim, pl(2), pl(3));

  auto mirror = [&](int u, int v) {
    mirror_k<<<8192, blk, 0, stream>>>(pl(u), pl(u + 1), pl(v), pl(v + 1));
  };
  // A2 = A @ A = -(A A^H) (Hermitian, upper tiles; YNEG=2) -> P0
  {
    MGP G{};
    set2(G.X[0], 0); set2(G.X[1], 2);
    set2(G.Y[0], 0); set2(G.Y[1], 2);
    set2o(G.O[0], 4); set2o(G.O[1], 6);
    G.M = G.K = G.N = G.Kx = 1024;
    mgemm_k<2,2,2,1,0,0,0,1,2><<<gTRI, blk, 0, stream>>>(G);
  }
  mirror(4, 6);
  // T0 = I + 2A + A2
  t02_k<<<4096, blk, 0, stream>>>(pl(0), pl(1), pl(4), pl(5), pl(12), pl(13));
  t02_k<<<4096, blk, 0, stream>>>(pl(2), pl(3), pl(6), pl(7), pl(14), pl(15));

  auto chain_pow = [&](int xu, int xv, int ou, int ov) {  // P' = P P^H (Herm, upper)
    MGP G{};
    set2(G.X[0], xu); set2(G.X[1], xv);
    set2(G.Y[0], xu); set2(G.Y[1], xv);
    set2o(G.O[0], ou); set2o(G.O[1], ov);
    G.M = G.K = G.N = G.Kx = 1024;
    mgemm_k<2,2,2,1,0,0,0,1,1><<<gTRI, blk, 0, stream>>>(G);
    mirror(ou, ov);
  };
  auto chain_t = [&](int xu, int xv, int yu, int yv, int ou, int ov) {  // T' = T + T@P
    MGP G{};
    set2(G.X[0], xu); set2(G.X[1], xv);
    set2(G.Y[0], yu); set2(G.Y[1], yv);
    set2o(G.O[0], ou); set2o(G.O[1], ov);
    G.M = G.K = G.N = G.Kx = 1024;
    mgemm_k<2,2,2,0,0,1,0,1,1><<<gFULL, blk, 0, stream>>>(G);
  };
  chain_pow(4, 6, 8, 10);             // A4  = A2*A2    -> P1
  chain_t(12, 14, 4, 6, 16, 18);      // T1  = T0(I+A2)  -> Tb1
  chain_pow(8, 10, 4, 6);             // A8  = A4*A4    -> P0
  chain_t(16, 18, 8, 10, 12, 14);     // T2  = T1(I+A4)  -> Tb0
  chain_pow(4, 6, 8, 10);             // A16 = A8*A8    -> P1
  chain_t(12, 14, 4, 6, 16, 18);      // T3  = T2(I+A8)  -> Tb1
  chain_t(16, 18, 8, 10, 20, 22);     // T4  = T3(I+A16) -> U(20-21)/V(22-23)

  // ---- fp32 small path ----
  ops_k<<<4, blk, 0, stream>>>(ld_, lf_, lawre, lawim, dtp, odr, odi, ofr, ofi);
  mlpw_k<false><<<8192, blk, 0, stream>>>(xg_re, xg_im, mixw, mixb, xm, nullptr);
  flux_k<<<64, blk, 0, stream>>>(fl_re, fl_im, dcre, dcim, xm, fnre, fnim, outf);
  mlpw_k<true><<<8192, blk, 0, stream>>>(fnre, fnim, projw, projb, sre, sim);
  srcf_k<<<64, blk, 0, stream>>>(sre, sim, ofr, ofi, sfre, sfim);

  // ---- Minv = (V s^-1) conj(U)^T -> 4-5 ; M = (U s) conj(V)^T -> 6-7 ----
  colscale2_k<<<4096, blk, 0, stream>>>(pl(22), pl(23), lsig, -1.f, pl(0), pl(1)); // XscV
  colscale2_k<<<4096, blk, 0, stream>>>(pl(20), pl(21), lsig, +1.f, pl(2), pl(3)); // XscU
  {
    MGP G{};
    set2(G.X[0], 0); set2(G.X[1], 2);
    set2(G.Y[0], 20); set2(G.Y[1], 22);   // conj via YNEG=1
    set2o(G.O[0], 4); set2o(G.O[1], 6);
    G.M = G.K = G.N = G.Kx = 1024;
    mgemm_k<2,2,2,0,0,0,0,1,1><<<gFULL, blk, 0, stream>>>(G);
  }
  // W1 [1024][2048] = [Minv*od | Minv*of], re at 8-9, im at 10-11
  w1build_k<<<4096, blk, 0, stream>>>(pl(4), pl(5), odr, odi, ofr, ofi, pl(8), pl(10));
  // h, x -> single-bf16 planes (after MinvM: xp overwrites U/V)
  conv2_k<<<16384, blk, 0, stream>>>(h_re, h_im, pl(12), pl(16));
  conv2_k<<<16384, blk, 0, stream>>>(x_re, x_im, pl(20), pl(24));

  // ---- big GEMM 1: ht = [h|x] @ [W1d;W1f] + srcf -> single-bf16 ht ----
  {
    MGP G{};
    G.X[0][0] = pl(12); G.X[0][1] = pl(16);
    G.X2p[0][0] = pl(20); G.X2p[0][1] = pl(24);
    G.Y[0][0] = pl(8); G.Y[0][1] = pl(10);
    G.O[0][0] = pl(28); G.O[0][1] = pl(32);
    G.S[0][0] = sfre; G.S[0][1] = sfim;
    G.M = 4096; G.K = 2048; G.N = 1024; G.Kx = 1024;
    mgemm_k<4,2,2,0,1,0,1,1,0><<<dim3(16, 32, 1), blk, 0, stream>>>(G);
  }
  // ---- big GEMM 2: out = ht @ M^T -> fp32 d_out ----
  {
    MGP G{};
    G.X[0][0] = pl(28); G.X[0][1] = pl(32);
    G.Y[0][0] = pl(6); G.Y[0][1] = pl(7);
    G.OF[0][0] = outf; G.OF[0][1] = outf + TBD;
    G.M = 4096; G.K = 1024; G.N = 1024; G.Kx = 1024;
    mgemm_k<4,2,2,0,0,0,0,2,0><<<dim3(16, 32, 1), blk, 0, stream>>>(G);
  }
}